// Round 12
// baseline (1549.133 us; speedup 1.0000x reference)
//
#include <hip/hip_runtime.h>
#include <hip/hip_fp16.h>

// ManualRNN: B=32, T=2048, Fin=256, H=256, O=256 (all f32 in/out)
// SINGLE dispatch, 32 blocks (1/batch) x 512 thr (8 waves), 3 sequential phases:
//   boot: xh(f16) = x[b]@Wxh^T + bxh -> 2nd half of batch b's OWN y slice
//         (1MB; self-clobbered by tail AFTER scan - no cross-block aliasing)
//   scan: h_t = tanh(xh_t + h@Whh^T)  [r10 body verbatim, 799us verified]
//         -> hs f16 in d_ws
//   tail: y[b](f32) = hs[b]@Why^T + by  (overwrites the dead xh region)
// h_final at d_out + 65536*256.
//
// Ledger: scan step = 933cy = 620cy MFMA-issue floor (128 MFMA/block-step,
// config-invariant) + ~313cy serial recurrence tail. r5: LDS spin-poll >
// barrier. r8: VALU path 2x (cvt+fma codegen). r9: IN-LOOP y-trickle register
// pressure wrecked scan codegen; boot phase itself was fine -> fuse phases
// OUTSIDE the loop only. r10/r11: separate GEMMs+gaps pinned at ~121us across
// configs (roofline ~16us each) -> overhead-dominated -> fuse to 1 dispatch.

typedef _Float16 f16x8 __attribute__((ext_vector_type(8)));
typedef float    f32x4 __attribute__((ext_vector_type(4)));

#define MFMA16 __builtin_amdgcn_mfma_f32_16x16x32_f16

__device__ __forceinline__ f16x8 cvt8(const float* __restrict__ p) {
    float4 u = *(const float4*)p;
    float4 v = *(const float4*)(p + 4);
    f16x8 r;
    r[0] = (_Float16)u.x; r[1] = (_Float16)u.y; r[2] = (_Float16)u.z; r[3] = (_Float16)u.w;
    r[4] = (_Float16)v.x; r[5] = (_Float16)v.y; r[6] = (_Float16)v.z; r[7] = (_Float16)v.w;
    return r;
}

__global__ __launch_bounds__(512, 1) void rnn_fused(
    const float* __restrict__ x,   const float* __restrict__ h0,
    const float* __restrict__ Wxh, const float* __restrict__ bxh,
    const float* __restrict__ Whh, const float* __restrict__ Why,
    const float* __restrict__ by,
    float* __restrict__ y,         // (65536,256) f32
    float* __restrict__ hfin,      // (32,256) f32
    _Float16* __restrict__ hs) {   // d_ws: (65536,256) f16
    const int b   = blockIdx.x;
    const int tid = threadIdx.x;
    const int l   = tid & 63;
    const int w   = tid >> 6;   // 0..7
    const int lr  = l & 15;
    const int lg  = l >> 4;
    const int n0  = w * 32;
    const int cl  = n0 + (l & 31);

    __shared__ _Float16 hbuf[2][256];

    const float* xb  = x  + (long)b * 2048 * 256;
    float*       yb  = y  + (long)b * 2048 * 256;
    _Float16*    hpB = hs + (long)b * 2048 * 256;
    // batch b's xh (f16, 1MB) in the second half of batch b's own y slice:
    // written by boot, read by scan, overwritten by this block's own tail.
    _Float16*    xhf = (_Float16*)(yb + (long)1024 * 256);

    // ---- boot: xh = x[b] @ Wxh^T + bxh ----
    {
        f16x8 wgx[2][8];
        #pragma unroll
        for (int nt = 0; nt < 2; ++nt)
            #pragma unroll
            for (int k = 0; k < 8; ++k)
                wgx[nt][k] = cvt8(Wxh + (long)(n0 + nt * 16 + lr) * 256 + k * 32 + lg * 8);
        const float bv0 = bxh[n0 + lr];
        const float bv1 = bxh[n0 + 16 + lr];

        #pragma unroll 2
        for (int mt = 0; mt < 128; ++mt) {
            f32x4 ac[2] = {{0.f,0.f,0.f,0.f},{0.f,0.f,0.f,0.f}};
            #pragma unroll
            for (int k = 0; k < 8; ++k) {
                const int kc = k * 32 + lg * 8;
                f16x8 a = cvt8(xb + (long)(mt * 16 + lr) * 256 + kc);
                ac[0] = MFMA16(a, wgx[0][k], ac[0], 0, 0, 0);
                ac[1] = MFMA16(a, wgx[1][k], ac[1], 0, 0, 0);
            }
            #pragma unroll
            for (int nt = 0; nt < 2; ++nt) {
                const int col = n0 + nt * 16 + lr;
                const float bv = nt ? bv1 : bv0;
                #pragma unroll
                for (int d = 0; d < 4; ++d)
                    xhf[(long)(mt * 16 + lg * 4 + d) * 256 + col] =
                        (_Float16)(ac[nt][d] + bv);
            }
        }
    }

    if (tid < 256) hbuf[0][tid] = (_Float16)h0[b * 256 + tid];
    __syncthreads();   // vmcnt drain: xh visible block-wide; hbuf ready

    // ---- scan (r10 body verbatim) ----
    {
        f16x8 wb[2][8];
        #pragma unroll
        for (int nt = 0; nt < 2; ++nt)
            #pragma unroll
            for (int k = 0; k < 8; ++k)
                wb[nt][k] = cvt8(Whh + (long)(n0 + nt * 16 + lr) * 256 + k * 32 + lg * 8);

        const _Float16* xp = xhf + cl;
        _Float16*       hp = hpB + cl;

        float xcur[4], xnext[4];
        #pragma unroll
        for (int j = 0; j < 4; ++j) xcur[j] = (float)xp[(long)j * 256];

        for (int tb = 0; tb < 2048; tb += 4) {
            #pragma unroll
            for (int j = 0; j < 4; ++j) {
                long tn = tb + 4 + j; if (tn > 2047) tn = 2047;
                xnext[j] = (float)xp[tn * 256];
            }

            #pragma unroll
            for (int j = 0; j < 4; ++j) {
                const f16x8* hc = (const f16x8*)hbuf[j & 1];   // t&1 == j&1
                f16x8 af[8];
                #pragma unroll
                for (int k = 0; k < 8; ++k) af[k] = hc[k * 4 + lg];

                __builtin_amdgcn_s_setprio(1);
                const f32x4 zero = {0.f, 0.f, 0.f, 0.f};
                f32x4 accA[2], accB[2];              // split chains k0-3 / k4-7
                #pragma unroll
                for (int nt = 0; nt < 2; ++nt) {
                    accA[nt] = MFMA16(af[0], wb[nt][0], zero, 0, 0, 0);
                    accB[nt] = MFMA16(af[4], wb[nt][4], zero, 0, 0, 0);
                }
                #pragma unroll
                for (int k = 1; k < 4; ++k)
                    #pragma unroll
                    for (int nt = 0; nt < 2; ++nt) {
                        accA[nt] = MFMA16(af[k],     wb[nt][k],     accA[nt], 0, 0, 0);
                        accB[nt] = MFMA16(af[k + 4], wb[nt][k + 4], accB[nt], 0, 0, 0);
                    }
                __builtin_amdgcn_s_setprio(0);

                const float s0 = accA[0][0] + accB[0][0];
                const float s1 = accA[1][0] + accB[1][0];
                const float s  = ((l & 16) ? s1 : s0) + xcur[j];
                const float e  = __expf(2.0f * s);
                const float v  = 1.0f - 2.0f * __builtin_amdgcn_rcpf(e + 1.0f);
                const _Float16 hv = (_Float16)v;

                if (l < 32) {
                    hbuf[(j & 1) ^ 1][cl] = hv;              // next step's h
                    hp[(long)(tb + j) * 256] = hv;           // fire-and-forget
                }

                asm volatile("s_waitcnt lgkmcnt(0)" ::: "memory");
                __builtin_amdgcn_s_barrier();
                asm volatile("" ::: "memory");
            }

            #pragma unroll
            for (int j = 0; j < 4; ++j) xcur[j] = xnext[j];
        }

        // t=2047 wrote parity ((2047&1)^1)=0
        if (tid < 256) hfin[b * 256 + tid] = (float)hbuf[0][tid];
    }

    __syncthreads();   // vmcnt drain: all waves' hs stores visible block-wide

    // ---- tail: y[b] = hs[b] @ Why^T + by ----
    {
        f16x8 wgy[2][8];
        #pragma unroll
        for (int nt = 0; nt < 2; ++nt)
            #pragma unroll
            for (int k = 0; k < 8; ++k)
                wgy[nt][k] = cvt8(Why + (long)(n0 + nt * 16 + lr) * 256 + k * 32 + lg * 8);
        const float bv0 = by[n0 + lr];
        const float bv1 = by[n0 + 16 + lr];

        #pragma unroll 2
        for (int mt = 0; mt < 128; ++mt) {
            f32x4 ac[2] = {{0.f,0.f,0.f,0.f},{0.f,0.f,0.f,0.f}};
            #pragma unroll
            for (int k = 0; k < 8; ++k) {
                const int kc = k * 32 + lg * 8;
                f16x8 a = *(const f16x8*)(hpB + (long)(mt * 16 + lr) * 256 + kc);
                ac[0] = MFMA16(a, wgy[0][k], ac[0], 0, 0, 0);
                ac[1] = MFMA16(a, wgy[1][k], ac[1], 0, 0, 0);
            }
            #pragma unroll
            for (int nt = 0; nt < 2; ++nt) {
                const int col = n0 + nt * 16 + lr;
                const float bv = nt ? bv1 : bv0;
                #pragma unroll
                for (int d = 0; d < 4; ++d)
                    yb[(long)(mt * 16 + lg * 4 + d) * 256 + col] = ac[nt][d] + bv;
            }
        }
    }
}

extern "C" void kernel_launch(void* const* d_in, const int* in_sizes, int n_in,
                              void* d_out, int out_size, void* d_ws, size_t ws_size,
                              hipStream_t stream) {
    const float* x   = (const float*)d_in[0];
    const float* h0  = (const float*)d_in[1];
    const float* Wxh = (const float*)d_in[2];
    const float* bxh = (const float*)d_in[3];
    const float* Whh = (const float*)d_in[4];
    const float* Why = (const float*)d_in[5];
    const float* by  = (const float*)d_in[6];

    float* y    = (float*)d_out;
    float* hfin = y + (long)65536 * 256;
    _Float16* hs = (_Float16*)d_ws;

    rnn_fused<<<32, 512, 0, stream>>>(x, h0, Wxh, bxh, Whh, Why, by, y, hfin, hs);
}

// Round 13
// 926.637 us; speedup vs baseline: 1.6718x; 1.6718x over previous
//
#include <hip/hip_runtime.h>
#include <hip/hip_fp16.h>

// ManualRNN: B=32, T=2048, Fin=256, H=256, O=256 (all f32 in/out)
//   phase1: xh(f16) = x @ Wxh^T + bxh -> 2nd half of y region (SPLIT IN 2
//           dispatches this round: measures pure per-dispatch gap cost)
//   phase2: scan with cross-barrier pipelining (own-chunk preread)
//   phase3: y(f32) = hs @ Why^T + by
//
// Ledger: scan step 933cy = 620 MFMA-issue floor + ~313 serial (event model
// verified r4/r10: 120 post-barrier ds_read + ~50 epi chain + ~60 lgkm +
// ~50 barrier + retire tail). r5: spin-poll > barrier, but rotated-wb layout
// verified correct. r8: VALU 2x (cvt+fma codegen). r9+r12: boot+scan fusion
// breaks scan (+900cy/step) at ANY register count - fusion closed.
// r11: partial-line stores exonerated. GEMM+gap = 121us config-invariant.
// r13: (a) own-chunk preread before barrier fills the 120cy window;
//      (b) phase1 split 2x -> Δtotal isolates gap cost.

typedef _Float16 f16x8 __attribute__((ext_vector_type(8)));
typedef float    f32x4 __attribute__((ext_vector_type(4)));

#define MFMA16 __builtin_amdgcn_mfma_f32_16x16x32_f16

__device__ __forceinline__ f16x8 cvt8(const float* __restrict__ p) {
    float4 u = *(const float4*)p;
    float4 v = *(const float4*)(p + 4);
    f16x8 r;
    r[0] = (_Float16)u.x; r[1] = (_Float16)u.y; r[2] = (_Float16)u.z; r[3] = (_Float16)u.w;
    r[4] = (_Float16)v.x; r[5] = (_Float16)v.y; r[6] = (_Float16)v.z; r[7] = (_Float16)v.w;
    return r;
}

// C[m][n] = sum_k A[m][k]*W[n][k] + bias[n];  M-tile 128, N=K=256. (r11 verbatim)
template<bool AF16, bool OF16>
__global__ __launch_bounds__(512, 2) void gemm_nt_512(
    const void* __restrict__ Av, const float* __restrict__ W,
    const float* __restrict__ bias, void* __restrict__ Cv) {
    const int tid = threadIdx.x;
    const int l  = tid & 63;
    const int w  = tid >> 6;        // 0..7
    const int lr = l & 15;
    const int lg = l >> 4;
    const long m0 = (long)blockIdx.x * 128;
    const int  n0 = w * 32;

    __shared__ _Float16 st[8][16][40];   // [wave][row][32 cols + pad]

    f16x8 wg[2][8];
    #pragma unroll
    for (int nt = 0; nt < 2; ++nt)
        #pragma unroll
        for (int k = 0; k < 8; ++k)
            wg[nt][k] = cvt8(W + (long)(n0 + nt * 16 + lr) * 256 + k * 32 + lg * 8);

    const float bv0 = bias[n0 + lr];
    const float bv1 = bias[n0 + 16 + lr];

    #pragma unroll 2
    for (int mt = 0; mt < 8; ++mt) {
        const long r0 = m0 + mt * 16 + lr;
        f32x4 ac[2] = {{0.f,0.f,0.f,0.f},{0.f,0.f,0.f,0.f}};
        #pragma unroll
        for (int k = 0; k < 8; ++k) {
            const int kc = k * 32 + lg * 8;
            f16x8 a;
            if constexpr (AF16) a = *(const f16x8*)((const _Float16*)Av + r0 * 256 + kc);
            else                a = cvt8((const float*)Av + r0 * 256 + kc);
            ac[0] = MFMA16(a, wg[0][k], ac[0], 0, 0, 0);
            ac[1] = MFMA16(a, wg[1][k], ac[1], 0, 0, 0);
        }
        if constexpr (OF16) {
            #pragma unroll
            for (int nt = 0; nt < 2; ++nt) {
                const float bv = nt ? bv1 : bv0;
                #pragma unroll
                for (int d = 0; d < 4; ++d)
                    st[w][lg * 4 + d][nt * 16 + lr] = (_Float16)(ac[nt][d] + bv);
            }
            asm volatile("s_waitcnt lgkmcnt(0)" ::: "memory");
            const int row = l >> 2;
            const int q   = l & 3;
            f16x8 vv = *(const f16x8*)&st[w][row][q * 8];
            *( f16x8*)((_Float16*)Cv + (m0 + mt * 16 + row) * 256 + n0 + q * 8) = vv;
            asm volatile("s_waitcnt lgkmcnt(0)" ::: "memory");
        } else {
            #pragma unroll
            for (int nt = 0; nt < 2; ++nt) {
                const int col = n0 + nt * 16 + lr;
                const float bv = nt ? bv1 : bv0;
                #pragma unroll
                for (int d = 0; d < 4; ++d) {
                    const long row = m0 + mt * 16 + lg * 4 + d;
                    ((float*)Cv)[row * 256 + col] = ac[nt][d] + bv;
                }
            }
        }
    }
}

// Recurrence with cross-barrier software pipelining. 32 blocks x 512 thr.
// Rotated Whh frags (r5-verified): wbr[nt][i] = chunk k=(w+i)&7. At iter end:
// write own h-slice -> lgkmcnt(0) -> read OWN chunk's A-frag (intra-wave data,
// no barrier needed) -> barrier. Next iter: chunk-0 MFMAs issue at barrier+0
// (a0 already in registers), chunks 1-7 ds_reads pipeline under them.
__global__ __launch_bounds__(512, 1) void rnn_scan(
    const _Float16* __restrict__ xh, const float* __restrict__ h0,
    const float* __restrict__ Whh, _Float16* __restrict__ hs,
    float* __restrict__ hfin) {
    const int b   = blockIdx.x;
    const int tid = threadIdx.x;
    const int l   = tid & 63;
    const int w   = tid >> 6;   // 0..7
    const int lr  = l & 15;
    const int lg  = l >> 4;
    const int n0  = w * 32;
    const int cl  = n0 + (l & 31);

    __shared__ _Float16 hbuf[2][256];

    // rotated B fragments: wbr[nt][i] = Whh[n0+nt*16+lr][k*32+lg*8..], k=(w+i)&7
    f16x8 wbr[2][8];
    #pragma unroll
    for (int i = 0; i < 8; ++i) {
        const int k = (w + i) & 7;
        #pragma unroll
        for (int nt = 0; nt < 2; ++nt)
            wbr[nt][i] = cvt8(Whh + (long)(n0 + nt * 16 + lr) * 256 + k * 32 + lg * 8);
    }

    if (tid < 256) hbuf[0][tid] = (_Float16)h0[b * 256 + tid];
    __syncthreads();

    const _Float16* xp = xh + (long)b * 2048 * 256 + cl;
    _Float16*       hp = hs + (long)b * 2048 * 256 + cl;

    float xcur[4], xnext[4];
    #pragma unroll
    for (int j = 0; j < 4; ++j) xcur[j] = (float)xp[(long)j * 256];

    // prologue: own chunk of h_0 (chunk w) into registers
    f16x8 a0 = ((const f16x8*)hbuf[0])[w * 4 + lg];

    for (int tb = 0; tb < 2048; tb += 4) {
        // next group's xh loads: ~2500cy cover >> 900cy HBM latency
        #pragma unroll
        for (int j = 0; j < 4; ++j) {
            long tn = tb + 4 + j; if (tn > 2047) tn = 2047;
            xnext[j] = (float)xp[tn * 256];
        }

        #pragma unroll
        for (int j = 0; j < 4; ++j) {
            const f16x8* hc = (const f16x8*)hbuf[j & 1];   // t&1 == j&1
            const f32x4 zero = {0.f, 0.f, 0.f, 0.f};

            __builtin_amdgcn_s_setprio(1);
            // chunk 0 (own, preread last iter): issues at barrier+0
            f32x4 accA[2], accB[2];
            accA[0] = MFMA16(a0, wbr[0][0], zero, 0, 0, 0);
            accA[1] = MFMA16(a0, wbr[1][0], zero, 0, 0, 0);

            // chunks 1..7 via LDS broadcast; pipeline under chunk-0 MFMAs
            f16x8 af[7];
            #pragma unroll
            for (int i = 0; i < 7; ++i) af[i] = hc[((w + i + 1) & 7) * 4 + lg];

            accB[0] = MFMA16(af[0], wbr[0][1], zero, 0, 0, 0);
            accB[1] = MFMA16(af[0], wbr[1][1], zero, 0, 0, 0);
            accA[0] = MFMA16(af[1], wbr[0][2], accA[0], 0, 0, 0);
            accA[1] = MFMA16(af[1], wbr[1][2], accA[1], 0, 0, 0);
            accB[0] = MFMA16(af[2], wbr[0][3], accB[0], 0, 0, 0);
            accB[1] = MFMA16(af[2], wbr[1][3], accB[1], 0, 0, 0);
            accA[0] = MFMA16(af[3], wbr[0][4], accA[0], 0, 0, 0);
            accA[1] = MFMA16(af[3], wbr[1][4], accA[1], 0, 0, 0);
            accB[0] = MFMA16(af[4], wbr[0][5], accB[0], 0, 0, 0);
            accB[1] = MFMA16(af[4], wbr[1][5], accB[1], 0, 0, 0);
            accA[0] = MFMA16(af[5], wbr[0][6], accA[0], 0, 0, 0);
            accA[1] = MFMA16(af[5], wbr[1][6], accA[1], 0, 0, 0);
            accB[0] = MFMA16(af[6], wbr[0][7], accB[0], 0, 0, 0);
            accB[1] = MFMA16(af[6], wbr[1][7], accB[1], 0, 0, 0);
            __builtin_amdgcn_s_setprio(0);

            // tanh(s + xh) = 1 - 2/(exp(2s)+1); select col's sum first
            const float s0 = accA[0][0] + accB[0][0];
            const float s1 = accA[1][0] + accB[1][0];
            const float s  = ((l & 16) ? s1 : s0) + xcur[j];
            const float e  = __expf(2.0f * s);
            const float v  = 1.0f - 2.0f * __builtin_amdgcn_rcpf(e + 1.0f);
            const _Float16 hv = (_Float16)v;

            if (l < 32) hbuf[(j & 1) ^ 1][cl] = hv;      // publish h_{t+1}
            // own-slice write retired, then preread own chunk of h_{t+1}
            // (intra-wave: producers are lanes 0-31 of THIS wave)
            asm volatile("s_waitcnt lgkmcnt(0)" ::: "memory");
            a0 = ((const f16x8*)hbuf[(j & 1) ^ 1])[w * 4 + lg];

            if (l < 32) hp[(long)(tb + j) * 256] = hv;   // fire-and-forget

            // LDS-only barrier (no vmcnt drain); a0 latency hides under
            // other waves' epilogues + barrier wait
            asm volatile("s_waitcnt lgkmcnt(0)" ::: "memory");
            __builtin_amdgcn_s_barrier();
            asm volatile("" ::: "memory");
        }

        #pragma unroll
        for (int j = 0; j < 4; ++j) xcur[j] = xnext[j];
    }

    // t=2047 wrote parity ((2047&1)^1)=0
    if (tid < 256) hfin[b * 256 + tid] = (float)hbuf[0][tid];
}

extern "C" void kernel_launch(void* const* d_in, const int* in_sizes, int n_in,
                              void* d_out, int out_size, void* d_ws, size_t ws_size,
                              hipStream_t stream) {
    const float* x   = (const float*)d_in[0];
    const float* h0  = (const float*)d_in[1];
    const float* Wxh = (const float*)d_in[2];
    const float* bxh = (const float*)d_in[3];
    const float* Whh = (const float*)d_in[4];
    const float* Why = (const float*)d_in[5];
    const float* by  = (const float*)d_in[6];

    float* y    = (float*)d_out;                   // (65536,256) f32
    float* hfin = y + (long)65536 * 256;           // (32,256) f32
    _Float16* xhf = (_Float16*)(y + (long)32768 * 256);  // xh f16, dead before phase3 writes
    _Float16* hs  = (_Float16*)d_ws;               // (65536,256) f16

    // phase1 SPLIT into two half-M dispatches: Δtotal vs r11 ≈ pure gap cost
    gemm_nt_512<false, true ><<<256, 512, 0, stream>>>(x, Wxh, bxh, xhf);
    gemm_nt_512<false, true ><<<256, 512, 0, stream>>>(
        x + (long)32768 * 256, Wxh, bxh, xhf + (long)32768 * 256);
    // phase2: scan
    rnn_scan<<<32, 512, 0, stream>>>(xhf, h0, Whh, hs, hfin);
    // phase3: y(f32) = hs @ Why^T + by
    gemm_nt_512<true,  false><<<512, 512, 0, stream>>>(hs, Why, by, y);
}